// Round 4
// baseline (29225.375 us; speedup 1.0000x reference)
//
#include <hip/hip_runtime.h>
#include <hip/hip_bf16.h>
#include <stdint.h>

typedef unsigned short u16;
typedef __bf16 bf16x8 __attribute__((ext_vector_type(8)));
typedef float f32x4 __attribute__((ext_vector_type(4)));

#define NT 365
#define NNODE 4096

__device__ __forceinline__ u16 f2b(float f) {
  __bf16 b = (__bf16)f;
  return __builtin_bit_cast(u16, b);
}
__device__ __forceinline__ float sigmoid_(float x) { return 1.f / (1.f + __expf(-x)); }
__device__ __forceinline__ float tanh_(float x) {
  float ax = fabsf(x);
  float e = __expf(-2.f * ax);
  float r = (1.f - e) / (1.f + e);
  return copysignf(r, x);
}

__device__ __forceinline__ void gload_lds16(const void* g, void* l) {
  __builtin_amdgcn_global_load_lds((const __attribute__((address_space(1))) void*)g,
                                   (__attribute__((address_space(3))) void*)l, 16, 0, 0);
}

// Stage RT rows x 64 bf16 cols into LDS. LDS dest linear (global_load_lds
// requirement); k-chunk XOR-swizzled on the GLOBAL source so the swizzled
// ds_read_b128 (frag_ld) is bank-conflict-free. gstride in elements.
template <int RT, int NTH>
__device__ __forceinline__ void stage_tile(const u16* __restrict__ g, int gstride,
                                           u16* lds, int tid) {
  constexpr int ITERS = (RT * 128) / (NTH * 16);
#pragma unroll
  for (int i = 0; i < ITERS; ++i) {
    int slot = i * NTH + tid;
    int off = slot << 4;               // LDS byte offset (linear)
    int row = off >> 7;                // 128 B per row (64 bf16)
    int k8 = ((off >> 4) & 7) ^ (row & 7);
    gload_lds16((const char*)(g + (size_t)row * gstride) + (k8 << 4), (char*)lds + off);
  }
}

// read 8 contiguous bf16 (one 16B chunk) for MFMA A/B fragment, undoing swizzle
__device__ __forceinline__ bf16x8 frag_ld(const u16* lds, int row, int q) {
  int off = (row << 7) + ((q ^ (row & 7)) << 4);
  return *(const bf16x8*)((const char*)lds + off);
}

__device__ __forceinline__ f32x4 mfma16(bf16x8 a, bf16x8 b, f32x4 c) {
  return __builtin_amdgcn_mfma_f32_16x16x32_bf16(a, b, c, 0, 0, 0);
}

// accumulate 8 bf16 (packed in uint4) into f[8] as f32
__device__ __forceinline__ void acc8(uint4 v, float* f) {
  f[0] += __builtin_bit_cast(float, v.x << 16);
  f[1] += __builtin_bit_cast(float, v.x & 0xffff0000u);
  f[2] += __builtin_bit_cast(float, v.y << 16);
  f[3] += __builtin_bit_cast(float, v.y & 0xffff0000u);
  f[4] += __builtin_bit_cast(float, v.z << 16);
  f[5] += __builtin_bit_cast(float, v.z & 0xffff0000u);
  f[6] += __builtin_bit_cast(float, v.w << 16);
  f[7] += __builtin_bit_cast(float, v.w & 0xffff0000u);
}

// ---------------- init kernels ----------------

__global__ void k_convA(const float* __restrict__ A, u16* __restrict__ Abf) {
  size_t i = ((size_t)blockIdx.x * 256 + threadIdx.x) * 8;
  float4 v0 = *(const float4*)(A + i);
  float4 v1 = *(const float4*)(A + i + 4);
  union { u16 u[8]; uint4 q; } o;
  o.u[0] = f2b(v0.x); o.u[1] = f2b(v0.y); o.u[2] = f2b(v0.z); o.u[3] = f2b(v0.w);
  o.u[4] = f2b(v1.x); o.u[5] = f2b(v1.y); o.u[6] = f2b(v1.z); o.u[7] = f2b(v1.w);
  *(uint4*)(Abf + i) = o.q;
}

__global__ void k_zero(float4* __restrict__ p) {
  p[(size_t)blockIdx.x * 256 + threadIdx.x] = make_float4(0.f, 0.f, 0.f, 0.f);
}

// x_0 into HX augmented cols [256,272)
__global__ void k_x0(const float* __restrict__ x, u16* __restrict__ HX) {
  int i = blockIdx.x * 256 + threadIdx.x;  // 65536
  int node = i >> 4, d = i & 15;
  HX[(size_t)node * 320 + 256 + d] = f2b(x[(size_t)node * (NT * 16) + d]);
}

// transpose+convert weights to bf16 B^T layouts. rkTa [1024][320] augmented:
// cols 0..255 = rkernel^T, 256..271 = kernel^T, 272..319 = 0.
__global__ void k_prep(const float* __restrict__ rk, const float* __restrict__ kern,
                       const float* __restrict__ wgh, const float* __restrict__ wgc,
                       const float* __restrict__ whc, const float* __restrict__ whp,
                       const float* __restrict__ wcc, const float* __restrict__ wcp,
                       u16* __restrict__ rkTa, u16* __restrict__ WgTh,
                       u16* __restrict__ WgTc, u16* __restrict__ WhT,
                       u16* __restrict__ WcT) {
  int i = blockIdx.x * 256 + threadIdx.x;
  if (i < 327680) {
    int j = i / 320, k = i % 320;
    float v = k < 256 ? rk[(size_t)k * 1024 + j]
                      : (k < 272 ? kern[(size_t)(k - 256) * 1024 + j] : 0.f);
    rkTa[i] = f2b(v);
    return;
  }
  i -= 327680;
  if (i < 65536) { int j = i >> 8, k = i & 255; WgTh[i] = f2b(wgh[k * 256 + j]); return; }
  i -= 65536;
  if (i < 65536) { int j = i >> 8, k = i & 255; WgTc[i] = f2b(wgc[k * 256 + j]); return; }
  i -= 65536;
  if (i < 131072) {
    int j = i >> 9, k = i & 511;
    WhT[i] = f2b(k < 256 ? whc[k * 256 + j] : whp[(k - 256) * 256 + j]);
    return;
  }
  i -= 131072;
  if (i < 131072) {
    int j = i >> 9, k = i & 511;
    WcT[i] = f2b(k < 256 ? wcc[k * 256 + j] : wcp[(k - 256) * 256 + j]);
  }
}

// ---------------- per-step kernels ----------------

// L1: Spb[s] = A @ HC over K-half s, bf16 partials. 128x128 tile, 8 waves of
// 32x64, raw-barrier 2-phase pipeline w/ counted vmcnt (never 0 mid-loop).
// grid 256 x 512thr. XCD decode: each XCD owns 4 m-slices (A L2-resident).
__global__ __launch_bounds__(512) void k_big(const u16* __restrict__ Abf,
                                             const u16* __restrict__ HCT,
                                             u16* __restrict__ Spb) {
  __shared__ __align__(16) u16 As[2][128 * 64];
  __shared__ __align__(16) u16 Bs[2][128 * 64];
  int bid = blockIdx.x;
  int xcd = bid & 7, idx = bid >> 3;
  int mb = xcd * 4 + (idx & 3), nb = (idx >> 2) & 3, sb = idx >> 4;
  int tid = threadIdx.x, lane = tid & 63, w = tid >> 6;
  int wr = w >> 1, wc = w & 1;  // 4x2 wave grid, wave tile 32x64
  int m0 = mb * 128, n0 = nb * 128, k0 = sb * 2048;
  f32x4 acc[2][4] = {};
  int ar = wr * 32 + (lane & 15);
  int bc = wc * 64 + (lane & 15);
  stage_tile<128, 512>(Abf + (size_t)m0 * 4096 + k0, 4096, As[0], tid);
  stage_tile<128, 512>(HCT + (size_t)n0 * 4096 + k0, 4096, Bs[0], tid);
  for (int kt = 0; kt < 32; ++kt) {
    int cb = kt & 1;
    if (kt < 31) {
      stage_tile<128, 512>(Abf + (size_t)m0 * 4096 + k0 + (kt + 1) * 64, 4096,
                           As[cb ^ 1], tid);
      stage_tile<128, 512>(HCT + (size_t)n0 * 4096 + k0 + (kt + 1) * 64, 4096,
                           Bs[cb ^ 1], tid);
      asm volatile("s_waitcnt vmcnt(4)" ::: "memory");  // cur tile landed (mine)
    } else {
      asm volatile("s_waitcnt vmcnt(0)" ::: "memory");
    }
    __builtin_amdgcn_s_barrier();                        // everyone's landed
#pragma unroll
    for (int kk = 0; kk < 2; ++kk) {
      int q = kk * 4 + (lane >> 4);
      bf16x8 a0 = frag_ld(As[cb], ar, q);
      bf16x8 a1 = frag_ld(As[cb], ar + 16, q);
      bf16x8 b[4];
#pragma unroll
      for (int n = 0; n < 4; ++n) b[n] = frag_ld(Bs[cb], bc + n * 16, q);
#pragma unroll
      for (int n = 0; n < 4; ++n) {
        acc[0][n] = mfma16(a0, b[n], acc[0][n]);
        acc[1][n] = mfma16(a1, b[n], acc[1][n]);
      }
    }
    asm volatile("" ::: "memory");
    __builtin_amdgcn_s_barrier();  // reads done before next overwrite
  }
  u16* out = Spb + (size_t)sb * (4096 * 512);
#pragma unroll
  for (int m = 0; m < 2; ++m)
#pragma unroll
    for (int n = 0; n < 4; ++n)
#pragma unroll
      for (int r = 0; r < 4; ++r) {
        int row = m0 + wr * 32 + m * 16 + ((lane >> 4) << 2) + r;
        int col = n0 + wc * 64 + n * 16 + (lane & 15);
        out[(size_t)row * 512 + col] = f2b(acc[m][n][r]);
      }
}

// L2: fully fused tail per 16-node stripe: gates + S-reduce + graph + merge +
// out_pred. Weights read as B-fragments directly from global (L2-resident).
// grid 256 x 512thr (8 waves; wave w owns h-cols w*32..w*32+31).
__global__ __launch_bounds__(512) void k_tail(
    const u16* __restrict__ Spb, u16* __restrict__ HX,
    const u16* __restrict__ rkTa, const u16* __restrict__ WgTh,
    const u16* __restrict__ WgTc, const u16* __restrict__ WhT,
    const u16* __restrict__ WcT, float* __restrict__ cf32,
    const float* __restrict__ lbias, const float* __restrict__ bgh,
    const float* __restrict__ bgc, const float* __restrict__ bh,
    const float* __restrict__ bcv, const float* __restrict__ wout,
    const float* __restrict__ bout, u16* __restrict__ HCT,
    float* __restrict__ dout, const float* __restrict__ xin, int t) {
  __shared__ __align__(16) u16 gA[5 * 1024];   // [5 panels][16][64]  h_prev|x
  __shared__ __align__(16) u16 gS[8 * 1024];   // [8][16][64]  S_h | S_c
  __shared__ __align__(16) u16 mAh[8 * 1024];  // [h_cur | h_graph]
  __shared__ __align__(16) u16 mAc[8 * 1024];  // [c_cur | c_graph]
  __shared__ float outac[32];
  int tid = threadIdx.x, lane = tid & 63, w = tid >> 6;
  int m0 = blockIdx.x * 16;
  int hc0 = w * 32;
  if (tid < 32) outac[tid] = 0.f;
  // stage gA: 640 16B chunks of HX rows [m0,m0+16) x 320 cols (swizzled src)
  {
    int c = tid;
    int p = c >> 7, r = (c >> 3) & 15, q = c & 7;
    gload_lds16(HX + (size_t)(m0 + r) * 320 + p * 64 + ((q ^ (r & 7)) << 3),
                (char*)gA + (c << 4));
    if (tid < 128) {
      int c2 = 512 + tid;
      int p2 = c2 >> 7, r2 = (c2 >> 3) & 15, q2 = c2 & 7;
      gload_lds16(HX + (size_t)(m0 + r2) * 320 + p2 * 64 + ((q2 ^ (r2 & 7)) << 3),
                  (char*)gA + (c2 << 4));
    }
  }
  // stage gS: reduce 2 bf16 split-K partials -> bf16, swizzled ds_write
#pragma unroll
  for (int i = 0; i < 2; ++i) {
    int c = i * 512 + tid;  // 1024 chunks: [8 panels][16 rows][8 q]
    int p = c >> 7, r = (c >> 3) & 15, q = c & 7;
    const u16* g = Spb + (size_t)(m0 + r) * 512 + p * 64 + q * 8;
    float f[8] = {};
    acc8(*(const uint4*)g, f);
    acc8(*(const uint4*)(g + (size_t)4096 * 512), f);
    union { u16 u[8]; uint4 v; } o;
#pragma unroll
    for (int e = 0; e < 8; ++e) o.u[e] = f2b(f[e]);
    *(uint4*)((char*)gS + (p << 11) + (r << 7) + ((q ^ (r & 7)) << 4)) = o.v;
  }
  __syncthreads();
  // ---- gates GEMM: [16,288] @ rkTa^T fragments (K=288 skips zero pad) ----
  f32x4 ga[4][2] = {};
#pragma unroll
  for (int kk = 0; kk < 9; ++kk) {
    int p = kk >> 1, q = (kk & 1) * 4 + (lane >> 4);
    bf16x8 a = frag_ld(gA + p * 1024, lane & 15, q);
#pragma unroll
    for (int seg = 0; seg < 4; ++seg)
#pragma unroll
      for (int nf = 0; nf < 2; ++nf) {
        int gcol = seg * 256 + hc0 + nf * 16 + (lane & 15);
        bf16x8 b = *(const bf16x8*)(rkTa + (size_t)gcol * 320 + kk * 32 +
                                    ((lane >> 4) << 3));
        ga[seg][nf] = mfma16(a, b, ga[seg][nf]);
      }
  }
  // gates epilogue -> h_cur/c_cur into mAh/mAc panels 0..3 (swizzled u16)
#pragma unroll
  for (int nf = 0; nf < 2; ++nf)
#pragma unroll
    for (int r = 0; r < 4; ++r) {
      int hcol = hc0 + nf * 16 + (lane & 15);
      int row = ((lane >> 4) << 2) + r;
      int node = m0 + row;
      float zi = ga[0][nf][r] + lbias[hcol];
      float zf = ga[1][nf][r] + lbias[256 + hcol];
      float zg = ga[2][nf][r] + lbias[512 + hcol];
      float zo = ga[3][nf][r] + lbias[768 + hcol];
      float cp = cf32[(size_t)node * 256 + hcol];
      float cc = sigmoid_(zf) * cp + sigmoid_(zi) * tanh_(zg);
      float hc = sigmoid_(zo) * tanh_(cc);
      int p = hcol >> 6, q8 = (hcol >> 3) & 7, e = hcol & 7;
      int off = (p << 11) + (row << 7) + ((q8 ^ (row & 7)) << 4) + (e << 1);
      *(u16*)((char*)mAh + off) = f2b(hc);
      *(u16*)((char*)mAc + off) = f2b(cc);
    }
  __syncthreads();
  // ---- graph GEMMs: tanh(S @ Wg + bg), h and c ----
  f32x4 gh[2] = {}, gc[2] = {};
#pragma unroll
  for (int kk = 0; kk < 8; ++kk) {
    int p = kk >> 1, q = (kk & 1) * 4 + (lane >> 4);
    bf16x8 ah = frag_ld(gS + p * 1024, lane & 15, q);
    bf16x8 ac_ = frag_ld(gS + (4 + p) * 1024, lane & 15, q);
#pragma unroll
    for (int nf = 0; nf < 2; ++nf) {
      int gcol = hc0 + nf * 16 + (lane & 15);
      bf16x8 b1 = *(const bf16x8*)(WgTh + (size_t)gcol * 256 + kk * 32 +
                                   ((lane >> 4) << 3));
      bf16x8 b2 = *(const bf16x8*)(WgTc + (size_t)gcol * 256 + kk * 32 +
                                   ((lane >> 4) << 3));
      gh[nf] = mfma16(ah, b1, gh[nf]);
      gc[nf] = mfma16(ac_, b2, gc[nf]);
    }
  }
#pragma unroll
  for (int nf = 0; nf < 2; ++nf)
#pragma unroll
    for (int r = 0; r < 4; ++r) {
      int hcol = hc0 + nf * 16 + (lane & 15);
      int row = ((lane >> 4) << 2) + r;
      float vh = tanh_(gh[nf][r] + bgh[hcol]);
      float vc = tanh_(gc[nf][r] + bgc[hcol]);
      int kcol = 256 + hcol;
      int p = kcol >> 6, q8 = (kcol >> 3) & 7, e = kcol & 7;
      int off = (p << 11) + (row << 7) + ((q8 ^ (row & 7)) << 4) + (e << 1);
      *(u16*)((char*)mAh + off) = f2b(vh);
      *(u16*)((char*)mAc + off) = f2b(vc);
    }
  __syncthreads();
  // ---- merge GEMMs: sigmoid([cur|graph] @ [Wcur;Wprev] + b) ----
  f32x4 mh[2] = {}, mc2[2] = {};
#pragma unroll
  for (int kk = 0; kk < 16; ++kk) {
    int p = kk >> 1, q = (kk & 1) * 4 + (lane >> 4);
    bf16x8 ah = frag_ld(mAh + p * 1024, lane & 15, q);
    bf16x8 ac_ = frag_ld(mAc + p * 1024, lane & 15, q);
#pragma unroll
    for (int nf = 0; nf < 2; ++nf) {
      int ncol = hc0 + nf * 16 + (lane & 15);
      bf16x8 b1 = *(const bf16x8*)(WhT + (size_t)ncol * 512 + kk * 32 +
                                   ((lane >> 4) << 3));
      bf16x8 b2 = *(const bf16x8*)(WcT + (size_t)ncol * 512 + kk * 32 +
                                   ((lane >> 4) << 3));
      mh[nf] = mfma16(ah, b1, mh[nf]);
      mc2[nf] = mfma16(ac_, b2, mc2[nf]);
    }
  }
  // merge epilogue: HX h-cols, cf32, HCT (both halves), out-pred partials
#pragma unroll
  for (int nf = 0; nf < 2; ++nf) {
    int hcol = hc0 + nf * 16 + (lane & 15);
    int g = lane >> 4;
    float w0 = wout[hcol * 2], w1 = wout[hcol * 2 + 1];
    ushort4 ph, pc;
#pragma unroll
    for (int r = 0; r < 4; ++r) {
      int row = (g << 2) + r, node = m0 + row;
      float hu = sigmoid_(mh[nf][r] + bh[hcol]);
      float cu = sigmoid_(mc2[nf][r] + bcv[hcol]);
      HX[(size_t)node * 320 + hcol] = f2b(hu);
      cf32[(size_t)node * 256 + hcol] = cu;
      ((u16*)&ph)[r] = f2b(hu);
      ((u16*)&pc)[r] = f2b(cu);
      float q0 = hu * w0, q1 = hu * w1;
#pragma unroll
      for (int off2 = 1; off2 < 16; off2 <<= 1) {
        q0 += __shfl_xor(q0, off2);
        q1 += __shfl_xor(q1, off2);
      }
      if ((lane & 15) == 0) {
        atomicAdd(&outac[row * 2], q0);
        atomicAdd(&outac[row * 2 + 1], q1);
      }
    }
    *(ushort4*)(HCT + (size_t)hcol * 4096 + m0 + (g << 2)) = ph;
    *(ushort4*)(HCT + (size_t)(256 + hcol) * 4096 + m0 + (g << 2)) = pc;
  }
  if (t + 1 < NT && tid < 256) {
    int row = tid >> 4, d = tid & 15;
    HX[(size_t)(m0 + row) * 320 + 256 + d] =
        f2b(xin[(size_t)(m0 + row) * (NT * 16) + (t + 1) * 16 + d]);
  }
  __syncthreads();
  if (tid < 32) {
    int row = tid >> 1, pp = tid & 1;
    dout[(size_t)(m0 + row) * (NT * 2) + t * 2 + pp] = outac[tid] + bout[pp];
  }
}

extern "C" void kernel_launch(void* const* d_in, const int* in_sizes, int n_in,
                              void* d_out, int out_size, void* d_ws, size_t ws_size,
                              hipStream_t stream) {
  (void)in_sizes; (void)n_in; (void)out_size; (void)ws_size;
  const float* inputs = (const float*)d_in[0];
  const float* A      = (const float*)d_in[1];
  const float* kern   = (const float*)d_in[2];
  const float* rk     = (const float*)d_in[3];
  const float* lbias  = (const float*)d_in[4];
  const float* wgh    = (const float*)d_in[5];
  const float* bgh    = (const float*)d_in[6];
  const float* wgc    = (const float*)d_in[7];
  const float* bgc    = (const float*)d_in[8];
  const float* whc    = (const float*)d_in[9];
  const float* whp    = (const float*)d_in[10];
  const float* bh     = (const float*)d_in[11];
  const float* wcc    = (const float*)d_in[12];
  const float* wcp    = (const float*)d_in[13];
  const float* bcv    = (const float*)d_in[14];
  const float* wout   = (const float*)d_in[15];
  const float* bout   = (const float*)d_in[16];
  float* dout = (float*)d_out;

  // Total 54,394,880 B -- guaranteed fit (R1 proved ws >= ~63 MB).
  char* p = (char*)d_ws;
  u16* Abf  = (u16*)p; p += (size_t)4096 * 4096 * 2;   // 33.55 MB
  u16* HX   = (u16*)p; p += (size_t)4096 * 320 * 2;    // [h(256)|x(16)|0(48)]
  u16* HCT  = (u16*)p; p += (size_t)4096 * 512 * 2;    // [512][4096] transposed
  float* cf32 = (float*)p; p += (size_t)4096 * 256 * 4;
  u16* Spb  = (u16*)p; p += (size_t)2 * 4096 * 512 * 2;  // bf16 split-K partials
  u16* rkTa = (u16*)p; p += (size_t)1024 * 320 * 2;    // augmented [rk;kern;0]
  u16* WgThp = (u16*)p; p += (size_t)65536 * 2;
  u16* WgTcp = (u16*)p; p += (size_t)65536 * 2;
  u16* WhTp  = (u16*)p; p += (size_t)131072 * 2;
  u16* WcTp  = (u16*)p; p += (size_t)131072 * 2;

  k_convA<<<8192, 256, 0, stream>>>(A, Abf);
  // zero HX + HCT + cf32 (contiguous, 11,010,048 B = 688,128 float4)
  k_zero<<<2688, 256, 0, stream>>>((float4*)HX);
  k_x0<<<256, 256, 0, stream>>>(inputs, HX);
  k_prep<<<2816, 256, 0, stream>>>(rk, kern, wgh, wgc, whc, whp, wcc, wcp,
                                   rkTa, WgThp, WgTcp, WhTp, WcTp);

  for (int t = 0; t < NT; ++t) {
    k_big<<<256, 512, 0, stream>>>(Abf, HCT, Spb);
    k_tail<<<256, 512, 0, stream>>>(Spb, HX, rkTa, WgThp, WgTcp, WhTp, WcTp,
                                    cf32, lbias, bgh, bgc, bh, bcv, wout, bout,
                                    HCT, dout, inputs, t);
  }
}

// Round 5
// 21414.256 us; speedup vs baseline: 1.3648x; 1.3648x over previous
//
#include <hip/hip_runtime.h>
#include <hip/hip_bf16.h>
#include <stdint.h>

typedef unsigned short u16;
typedef __bf16 bf16x8 __attribute__((ext_vector_type(8)));
typedef float f32x4 __attribute__((ext_vector_type(4)));

#define NT 365
#define NNODE 4096

__device__ __forceinline__ u16 f2b(float f) {
  __bf16 b = (__bf16)f;
  return __builtin_bit_cast(u16, b);
}
__device__ __forceinline__ float sigmoid_(float x) { return 1.f / (1.f + __expf(-x)); }
__device__ __forceinline__ float tanh_(float x) {
  float ax = fabsf(x);
  float e = __expf(-2.f * ax);
  float r = (1.f - e) / (1.f + e);
  return copysignf(r, x);
}

__device__ __forceinline__ void gload_lds16(const void* g, void* l) {
  __builtin_amdgcn_global_load_lds((const __attribute__((address_space(1))) void*)g,
                                   (__attribute__((address_space(3))) void*)l, 16, 0, 0);
}

// Stage RT rows x 64 bf16 cols into LDS. LDS dest linear (global_load_lds
// requirement); k-chunk XOR-swizzled on the GLOBAL source so the swizzled
// ds_read_b128 (frag_ld) is bank-conflict-free. gstride in elements.
template <int RT, int NTH>
__device__ __forceinline__ void stage_tile(const u16* __restrict__ g, int gstride,
                                           u16* lds, int tid) {
  constexpr int ITERS = (RT * 128) / (NTH * 16);
#pragma unroll
  for (int i = 0; i < ITERS; ++i) {
    int slot = i * NTH + tid;
    int off = slot << 4;               // LDS byte offset (linear)
    int row = off >> 7;                // 128 B per row (64 bf16)
    int k8 = ((off >> 4) & 7) ^ (row & 7);
    gload_lds16((const char*)(g + (size_t)row * gstride) + (k8 << 4), (char*)lds + off);
  }
}

// read 8 contiguous bf16 (one 16B chunk) for MFMA A/B fragment, undoing swizzle
__device__ __forceinline__ bf16x8 frag_ld(const u16* lds, int row, int q) {
  int off = (row << 7) + ((q ^ (row & 7)) << 4);
  return *(const bf16x8*)((const char*)lds + off);
}

__device__ __forceinline__ f32x4 mfma16(bf16x8 a, bf16x8 b, f32x4 c) {
  return __builtin_amdgcn_mfma_f32_16x16x32_bf16(a, b, c, 0, 0, 0);
}

// accumulate 8 bf16 (packed in uint4) into f[8] as f32
__device__ __forceinline__ void acc8(uint4 v, float* f) {
  f[0] += __builtin_bit_cast(float, v.x << 16);
  f[1] += __builtin_bit_cast(float, v.x & 0xffff0000u);
  f[2] += __builtin_bit_cast(float, v.y << 16);
  f[3] += __builtin_bit_cast(float, v.y & 0xffff0000u);
  f[4] += __builtin_bit_cast(float, v.z << 16);
  f[5] += __builtin_bit_cast(float, v.z & 0xffff0000u);
  f[6] += __builtin_bit_cast(float, v.w << 16);
  f[7] += __builtin_bit_cast(float, v.w & 0xffff0000u);
}

// ---------------- init kernels ----------------

__global__ void k_convA(const float* __restrict__ A, u16* __restrict__ Abf) {
  size_t i = ((size_t)blockIdx.x * 256 + threadIdx.x) * 8;
  float4 v0 = *(const float4*)(A + i);
  float4 v1 = *(const float4*)(A + i + 4);
  union { u16 u[8]; uint4 q; } o;
  o.u[0] = f2b(v0.x); o.u[1] = f2b(v0.y); o.u[2] = f2b(v0.z); o.u[3] = f2b(v0.w);
  o.u[4] = f2b(v1.x); o.u[5] = f2b(v1.y); o.u[6] = f2b(v1.z); o.u[7] = f2b(v1.w);
  *(uint4*)(Abf + i) = o.q;
}

__global__ void k_zero(float4* __restrict__ p) {
  p[(size_t)blockIdx.x * 256 + threadIdx.x] = make_float4(0.f, 0.f, 0.f, 0.f);
}

// x_0 into HX augmented cols [256,272)
__global__ void k_x0(const float* __restrict__ x, u16* __restrict__ HX) {
  int i = blockIdx.x * 256 + threadIdx.x;  // 65536
  int node = i >> 4, d = i & 15;
  HX[(size_t)node * 320 + 256 + d] = f2b(x[(size_t)node * (NT * 16) + d]);
}

// transpose+convert weights to bf16 B^T layouts. rkTa [1024][320] augmented:
// cols 0..255 = rkernel^T, 256..271 = kernel^T, 272..319 = 0.
__global__ void k_prep(const float* __restrict__ rk, const float* __restrict__ kern,
                       const float* __restrict__ wgh, const float* __restrict__ wgc,
                       const float* __restrict__ whc, const float* __restrict__ whp,
                       const float* __restrict__ wcc, const float* __restrict__ wcp,
                       u16* __restrict__ rkTa, u16* __restrict__ WgTh,
                       u16* __restrict__ WgTc, u16* __restrict__ WhT,
                       u16* __restrict__ WcT) {
  int i = blockIdx.x * 256 + threadIdx.x;
  if (i < 327680) {
    int j = i / 320, k = i % 320;
    float v = k < 256 ? rk[(size_t)k * 1024 + j]
                      : (k < 272 ? kern[(size_t)(k - 256) * 1024 + j] : 0.f);
    rkTa[i] = f2b(v);
    return;
  }
  i -= 327680;
  if (i < 65536) { int j = i >> 8, k = i & 255; WgTh[i] = f2b(wgh[k * 256 + j]); return; }
  i -= 65536;
  if (i < 65536) { int j = i >> 8, k = i & 255; WgTc[i] = f2b(wgc[k * 256 + j]); return; }
  i -= 65536;
  if (i < 131072) {
    int j = i >> 9, k = i & 511;
    WhT[i] = f2b(k < 256 ? whc[k * 256 + j] : whp[(k - 256) * 256 + j]);
    return;
  }
  i -= 131072;
  if (i < 131072) {
    int j = i >> 9, k = i & 511;
    WcT[i] = f2b(k < 256 ? wcc[k * 256 + j] : wcp[(k - 256) * 256 + j]);
  }
}

// ---------------- per-step kernels ----------------

// L1 hetero: bid < 128*nsplit -> big GEMM Spb[s] = A @ HC (K-split, bf16
// partials; 128x128 tile, 4 waves of 64x64, LDS dbuf) -- byte-identical to R3.
// bid >= 128*nsplit -> LSTM gates (augmented K=320), independent of k_big.
__global__ __launch_bounds__(256) void k_l1(
    const u16* __restrict__ Abf, const u16* __restrict__ HCT,
    u16* __restrict__ Spb, int nsplit, const u16* __restrict__ HX,
    const u16* __restrict__ rkTa, const float* __restrict__ cf32,
    const float* __restrict__ lbias, u16* __restrict__ HG, u16* __restrict__ CG) {
  __shared__ __align__(16) u16 As2[2][128 * 64];
  __shared__ __align__(16) u16 Bs2[2][128 * 64];
  int bid = blockIdx.x;
  int nbig = nsplit << 7;
  int tid = threadIdx.x, lane = tid & 63, w = tid >> 6;
  if (bid < nbig) {
    int mb, nb, sb;
    if (nsplit == 4) {
      int mhi = bid & 1, sp = (bid >> 1) & 3, rest = bid >> 3;
      mb = mhi * 16 + (rest & 15); nb = rest >> 4; sb = sp;
    } else {  // nsplit == 2
      mb = bid & 31; nb = (bid >> 5) & 3; sb = bid >> 7;
    }
    int kspan = 4096 / nsplit;
    int wr = w >> 1, wc = w & 1;
    int m0 = mb * 128, n0 = nb * 128, k0 = sb * kspan;
    f32x4 acc[4][4] = {};
    int ar = wr * 64 + (lane & 15);
    int bc = wc * 64 + (lane & 15);
    int nk = kspan >> 6;
    stage_tile<128, 256>(Abf + (size_t)m0 * 4096 + k0, 4096, As2[0], tid);
    stage_tile<128, 256>(HCT + (size_t)n0 * 4096 + k0, 4096, Bs2[0], tid);
    __syncthreads();
    for (int kt = 0; kt < nk; ++kt) {
      int cb = kt & 1;
      if (kt + 1 < nk) {
        stage_tile<128, 256>(Abf + (size_t)m0 * 4096 + k0 + (kt + 1) * 64, 4096,
                             As2[cb ^ 1], tid);
        stage_tile<128, 256>(HCT + (size_t)n0 * 4096 + k0 + (kt + 1) * 64, 4096,
                             Bs2[cb ^ 1], tid);
      }
#pragma unroll
      for (int kk = 0; kk < 2; ++kk) {
        int q = kk * 4 + (lane >> 4);
        bf16x8 a[4], b[4];
#pragma unroll
        for (int m = 0; m < 4; ++m) a[m] = frag_ld(As2[cb], ar + m * 16, q);
#pragma unroll
        for (int n = 0; n < 4; ++n) b[n] = frag_ld(Bs2[cb], bc + n * 16, q);
#pragma unroll
        for (int m = 0; m < 4; ++m)
#pragma unroll
          for (int n = 0; n < 4; ++n) acc[m][n] = mfma16(a[m], b[n], acc[m][n]);
      }
      __syncthreads();
    }
    u16* out = Spb + (size_t)sb * (4096 * 512);
#pragma unroll
    for (int m = 0; m < 4; ++m)
#pragma unroll
      for (int n = 0; n < 4; ++n)
#pragma unroll
        for (int r = 0; r < 4; ++r) {
          int row = m0 + wr * 64 + m * 16 + ((lane >> 4) << 2) + r;
          int col = n0 + wc * 64 + n * 16 + (lane & 15);
          out[(size_t)row * 512 + col] = f2b(acc[m][n][r]);
        }
  } else {
    // ---- gates: z = [h|x|0] @ rkTa + b ; h_cur,c_cur -> HG/CG cols 0..255 ----
    int gb = bid - nbig;
    int m0 = (gb & 63) * 64, c0 = (gb >> 6) * 64;
    u16* As = As2[0];          // 8 KB of the 32 KB
    u16* Bs = &Bs2[0][0];      // full 32 KB
    int wr = w >> 1, wc = w & 1;
    int ar = wr * 32 + (lane & 15);
    int bc = wc * 32 + (lane & 15);
    f32x4 acc[4][2][2] = {};
    for (int kt = 0; kt < 320; kt += 64) {
      stage_tile<64, 256>(HX + (size_t)m0 * 320 + kt, 320, As, tid);
#pragma unroll
      for (int i = 0; i < 8; ++i) {  // 4 gate segments x 64 rows of rkTa
        int slot = i * 256 + tid;
        int off = slot << 4;
        int row = off >> 7;
        int k8 = ((off >> 4) & 7) ^ (row & 7);
        int grow = ((row >> 6) << 8) + c0 + (row & 63);
        gload_lds16((const char*)(rkTa + (size_t)grow * 320 + kt) + (k8 << 4),
                    (char*)Bs + off);
      }
      __syncthreads();
#pragma unroll
      for (int kk = 0; kk < 2; ++kk) {
        int q = kk * 4 + (lane >> 4);
        bf16x8 a0 = frag_ld(As, ar, q);
        bf16x8 a1 = frag_ld(As, ar + 16, q);
#pragma unroll
        for (int s = 0; s < 4; ++s) {
          const u16* B = Bs + s * 4096;
          bf16x8 b0 = frag_ld(B, bc, q);
          bf16x8 b1 = frag_ld(B, bc + 16, q);
          acc[s][0][0] = mfma16(a0, b0, acc[s][0][0]);
          acc[s][0][1] = mfma16(a0, b1, acc[s][0][1]);
          acc[s][1][0] = mfma16(a1, b0, acc[s][1][0]);
          acc[s][1][1] = mfma16(a1, b1, acc[s][1][1]);
        }
      }
      __syncthreads();
    }
#pragma unroll
    for (int m = 0; m < 2; ++m)
#pragma unroll
      for (int r = 0; r < 4; ++r) {
        int node = m0 + wr * 32 + m * 16 + ((lane >> 4) << 2) + r;
#pragma unroll
        for (int n = 0; n < 2; ++n) {
          int hcol = c0 + wc * 32 + n * 16 + (lane & 15);
          float z0 = acc[0][m][n][r] + lbias[hcol];
          float z1 = acc[1][m][n][r] + lbias[256 + hcol];
          float z2 = acc[2][m][n][r] + lbias[512 + hcol];
          float z3 = acc[3][m][n][r] + lbias[768 + hcol];
          float i_ = sigmoid_(z0), f_ = sigmoid_(z1);
          float g_ = tanh_(z2), o_ = sigmoid_(z3);
          float cp = cf32[(size_t)node * 256 + hcol];
          float cc = f_ * cp + i_ * g_;
          float hc = o_ * tanh_(cc);
          HG[(size_t)node * 512 + hcol] = f2b(hc);
          CG[(size_t)node * 512 + hcol] = f2b(cc);
        }
      }
  }
}

// L2: graph GEMM out = tanh(S_half @ Wg + bg), split-K reduce fused into
// A-staging. m-tile 32: grid 1024 x 256thr (4 blocks/CU, 16 waves/CU).
__global__ __launch_bounds__(256) void k_graph(
    const u16* __restrict__ Spb, int nsplit, const u16* __restrict__ WgTh,
    const u16* __restrict__ WgTc, const float* __restrict__ bgh,
    const float* __restrict__ bgc, u16* __restrict__ HG, u16* __restrict__ CG) {
  __shared__ __align__(16) u16 As[32 * 64];   // 4 KB
  __shared__ __align__(16) u16 Bs[64 * 64];   // 8 KB
  int bid = blockIdx.x, tid = threadIdx.x, lane = tid & 63, w = tid >> 6;
  int zz = bid >> 9;
  int rest = bid & 511;
  int c0 = (rest >> 7) * 64, m0 = (rest & 127) * 32;
  const u16* WT = zz ? WgTc : WgTh;
  const float* bg = zz ? bgc : bgh;
  u16* outp = zz ? CG : HG;
  f32x4 acc[2] = {};
  for (int kt = 0; kt < 256; kt += 64) {
    // A-stage: reduce nsplit bf16 partials -> bf16, swizzled ds_write (256 chunks)
    {
      int srow = tid >> 3, sq = tid & 7;
      const u16* g = Spb + (size_t)(m0 + srow) * 512 + zz * 256 + kt + sq * 8;
      float f[8] = {};
      for (int s = 0; s < nsplit; ++s)
        acc8(*(const uint4*)(g + (size_t)s * (4096 * 512)), f);
      union { u16 u[8]; uint4 v; } o;
#pragma unroll
      for (int e = 0; e < 8; ++e) o.u[e] = f2b(f[e]);
      *(uint4*)((char*)As + (srow << 7) + ((sq ^ (srow & 7)) << 4)) = o.v;
    }
    stage_tile<64, 256>(WT + (size_t)c0 * 256 + kt, 256, Bs, tid);
    __syncthreads();
#pragma unroll
    for (int kk = 0; kk < 2; ++kk) {
      int q = kk * 4 + (lane >> 4);
      bf16x8 b = frag_ld(Bs, w * 16 + (lane & 15), q);
      bf16x8 a0 = frag_ld(As, lane & 15, q);
      bf16x8 a1 = frag_ld(As, 16 + (lane & 15), q);
      acc[0] = mfma16(a0, b, acc[0]);
      acc[1] = mfma16(a1, b, acc[1]);
    }
    __syncthreads();
  }
#pragma unroll
  for (int m = 0; m < 2; ++m)
#pragma unroll
    for (int r = 0; r < 4; ++r) {
      int row = m0 + m * 16 + ((lane >> 4) << 2) + r;
      int col = c0 + w * 16 + (lane & 15);
      outp[(size_t)row * 512 + 256 + col] = f2b(tanh_(acc[m][r] + bg[col]));
    }
}

// L3: h_upd/c_upd = sigmoid([cur|graph] @ [Wcur;Wprev] + b). m-tile 16:
// grid(256,2) x 256thr (2 blocks/CU). z=0 emits out_pred + HX h-cols + x_{t+1}.
__global__ __launch_bounds__(256) void k_merge(
    const u16* __restrict__ HG, const u16* __restrict__ CG,
    const u16* __restrict__ WhT, const u16* __restrict__ WcT,
    const float* __restrict__ bh, const float* __restrict__ bcv,
    const float* __restrict__ Wout, const float* __restrict__ bout,
    u16* __restrict__ HX, u16* __restrict__ HCT, float* __restrict__ cf32,
    float* __restrict__ dout, const float* __restrict__ xin, int t) {
  __shared__ __align__(16) u16 As[16 * 64];    // 2 KB
  __shared__ __align__(16) u16 Bs[256 * 64];   // 32 KB
  __shared__ float outac[32];
  int z = blockIdx.y;
  const u16* Ain = z ? CG : HG;
  const u16* WT = z ? WcT : WhT;
  const float* bb = z ? bcv : bh;
  int tid = threadIdx.x, lane = tid & 63, w = tid >> 6;
  int m0 = blockIdx.x * 16;
  if (tid < 32) outac[tid] = 0.f;
  f32x4 acc[4] = {};
  int bcol = w * 64 + (lane & 15);
  for (int kt = 0; kt < 512; kt += 64) {
    // A-stage: 128 chunks (16 rows x 8 q), swizzled source
    if (tid < 128) {
      int row = tid >> 3, q = tid & 7;
      int k8 = q ^ (row & 7);
      gload_lds16(Ain + (size_t)(m0 + row) * 512 + kt + k8 * 8,
                  (char*)As + (tid << 4));
    }
    stage_tile<256, 256>(WT + kt, 512, Bs, tid);
    __syncthreads();
#pragma unroll
    for (int kk = 0; kk < 2; ++kk) {
      int q = kk * 4 + (lane >> 4);
      bf16x8 a0 = frag_ld(As, lane & 15, q);
      bf16x8 b0 = frag_ld(Bs, bcol, q);
      bf16x8 b1 = frag_ld(Bs, bcol + 16, q);
      bf16x8 b2 = frag_ld(Bs, bcol + 32, q);
      bf16x8 b3 = frag_ld(Bs, bcol + 48, q);
      acc[0] = mfma16(a0, b0, acc[0]);
      acc[1] = mfma16(a0, b1, acc[1]);
      acc[2] = mfma16(a0, b2, acc[2]);
      acc[3] = mfma16(a0, b3, acc[3]);
    }
    __syncthreads();
  }
#pragma unroll
  for (int r = 0; r < 4; ++r) {
    int row_local = ((lane >> 4) << 2) + r;
    int node = m0 + row_local;
    float p0 = 0.f, p1 = 0.f;
#pragma unroll
    for (int n = 0; n < 4; ++n) {
      int col = w * 64 + n * 16 + (lane & 15);
      float v = sigmoid_(acc[n][r] + bb[col]);
      if (z == 0) {
        HX[(size_t)node * 320 + col] = f2b(v);
        HCT[(size_t)col * 4096 + node] = f2b(v);
        p0 += v * Wout[col * 2];
        p1 += v * Wout[col * 2 + 1];
      } else {
        HCT[(size_t)(256 + col) * 4096 + node] = f2b(v);
        cf32[(size_t)node * 256 + col] = v;
      }
    }
    if (z == 0) {
#pragma unroll
      for (int off2 = 1; off2 < 16; off2 <<= 1) {
        p0 += __shfl_xor(p0, off2);
        p1 += __shfl_xor(p1, off2);
      }
      if ((lane & 15) == 0) {
        atomicAdd(&outac[row_local * 2], p0);
        atomicAdd(&outac[row_local * 2 + 1], p1);
      }
    }
  }
  if (z == 0 && t + 1 < NT && tid < 256) {
    int row = tid >> 4, d = tid & 15;
    HX[(size_t)(m0 + row) * 320 + 256 + d] =
        f2b(xin[(size_t)(m0 + row) * (NT * 16) + (t + 1) * 16 + d]);
  }
  __syncthreads();
  if (z == 0 && tid < 32) {
    int row = tid >> 1, pp = tid & 1;
    dout[(size_t)(m0 + row) * (NT * 2) + t * 2 + pp] = outac[tid] + bout[pp];
  }
}

extern "C" void kernel_launch(void* const* d_in, const int* in_sizes, int n_in,
                              void* d_out, int out_size, void* d_ws, size_t ws_size,
                              hipStream_t stream) {
  (void)in_sizes; (void)n_in; (void)out_size;
  const float* inputs = (const float*)d_in[0];
  const float* A      = (const float*)d_in[1];
  const float* kern   = (const float*)d_in[2];
  const float* rk     = (const float*)d_in[3];
  const float* lbias  = (const float*)d_in[4];
  const float* wgh    = (const float*)d_in[5];
  const float* bgh    = (const float*)d_in[6];
  const float* wgc    = (const float*)d_in[7];
  const float* bgc    = (const float*)d_in[8];
  const float* whc    = (const float*)d_in[9];
  const float* whp    = (const float*)d_in[10];
  const float* bh     = (const float*)d_in[11];
  const float* wcc    = (const float*)d_in[12];
  const float* wcp    = (const float*)d_in[13];
  const float* bcv    = (const float*)d_in[14];
  const float* wout   = (const float*)d_in[15];
  const float* bout   = (const float*)d_in[16];
  float* dout = (float*)d_out;

  // layout: fixed part = 54.4 MB; Spb = nsplit*4.19 MB (bf16 partials)
  int nsplit = (ws_size >= 71200000) ? 4 : 2;

  char* p = (char*)d_ws;
  u16* Abf  = (u16*)p; p += (size_t)4096 * 4096 * 2;   // 33.55 MB
  u16* HX   = (u16*)p; p += (size_t)4096 * 320 * 2;    // [h(256)|x(16)|0(48)]
  u16* HCT  = (u16*)p; p += (size_t)4096 * 512 * 2;    // [512][4096] transposed
  float* cf32 = (float*)p; p += (size_t)4096 * 256 * 4;
  u16* Spb  = (u16*)p; p += (size_t)nsplit * 4096 * 512 * 2;  // bf16 partials
  u16* HG   = (u16*)p; p += (size_t)4096 * 512 * 2;    // [h_cur|h_graph]
  u16* CG   = (u16*)p; p += (size_t)4096 * 512 * 2;    // [c_cur|c_graph]
  u16* rkTa = (u16*)p; p += (size_t)1024 * 320 * 2;    // augmented [rk;kern;0]
  u16* WgThp = (u16*)p; p += (size_t)65536 * 2;
  u16* WgTcp = (u16*)p; p += (size_t)65536 * 2;
  u16* WhTp  = (u16*)p; p += (size_t)131072 * 2;
  u16* WcTp  = (u16*)p; p += (size_t)131072 * 2;

  k_convA<<<8192, 256, 0, stream>>>(A, Abf);
  // zero HX + HCT + cf32 (contiguous, 11,010,048 B = 688,128 float4)
  k_zero<<<2688, 256, 0, stream>>>((float4*)HX);
  k_x0<<<256, 256, 0, stream>>>(inputs, HX);
  k_prep<<<2816, 256, 0, stream>>>(rk, kern, wgh, wgc, whc, whp, wcc, wcp,
                                   rkTa, WgThp, WgTcp, WhTp, WcTp);

  for (int t = 0; t < NT; ++t) {
    k_l1<<<128 * nsplit + 256, 256, 0, stream>>>(Abf, HCT, Spb, nsplit, HX, rkTa,
                                                 cf32, lbias, HG, CG);
    k_graph<<<1024, 256, 0, stream>>>(Spb, nsplit, WgThp, WgTcp, bgh, bgc, HG, CG);
    k_merge<<<dim3(256, 2), 256, 0, stream>>>(HG, CG, WhTp, WcTp, bh, bcv, wout,
                                              bout, HX, HCT, cf32, dout, inputs, t);
  }
}

// Round 7
// 16228.914 us; speedup vs baseline: 1.8008x; 1.3195x over previous
//
#include <hip/hip_runtime.h>
#include <hip/hip_bf16.h>
#include <stdint.h>

typedef unsigned short u16;
typedef __bf16 bf16x8 __attribute__((ext_vector_type(8)));
typedef float f32x4 __attribute__((ext_vector_type(4)));
typedef int i32x8 __attribute__((ext_vector_type(8)));

#define NT 365
#define NNODE 4096

__device__ __forceinline__ u16 f2b(float f) {
  __bf16 b = (__bf16)f;
  return __builtin_bit_cast(u16, b);
}
__device__ __forceinline__ float sigmoid_(float x) { return 1.f / (1.f + __expf(-x)); }
__device__ __forceinline__ float tanh_(float x) {
  float ax = fabsf(x);
  float e = __expf(-2.f * ax);
  float r = (1.f - e) / (1.f + e);
  return copysignf(r, x);
}

// pack 4 floats -> 4 fp8 e4m3 (OCP on gfx950), bytes in order a,b,c,d
__device__ __forceinline__ unsigned int pk4_fp8(float a, float b, float c, float d) {
  int r = __builtin_amdgcn_cvt_pk_fp8_f32(a, b, 0, false);  // bytes 0,1
  r = __builtin_amdgcn_cvt_pk_fp8_f32(c, d, r, true);       // bytes 2,3
  return (unsigned int)r;
}

__device__ __forceinline__ void gload_lds16(const void* g, void* l) {
  __builtin_amdgcn_global_load_lds((const __attribute__((address_space(1))) void*)g,
                                   (__attribute__((address_space(3))) void*)l, 16, 0, 0);
}

// Stage RT rows x 64 bf16 cols into LDS (128B rows). LDS dest linear; k-chunk
// XOR-swizzled on the GLOBAL source so swizzled ds_read_b128 is conflict-free.
template <int RT, int NTH>
__device__ __forceinline__ void stage_tile(const u16* __restrict__ g, int gstride,
                                           u16* lds, int tid) {
  constexpr int ITERS = (RT * 128) / (NTH * 16);
#pragma unroll
  for (int i = 0; i < ITERS; ++i) {
    int slot = i * NTH + tid;
    int off = slot << 4;
    int row = off >> 7;
    int k8 = ((off >> 4) & 7) ^ (row & 7);
    gload_lds16((const char*)(g + (size_t)row * gstride) + (k8 << 4), (char*)lds + off);
  }
}

// byte version: 128 rows x 128 B (fp8 tiles), same swizzle
template <int NTH>
__device__ __forceinline__ void stage8(const char* __restrict__ g, int gstride,
                                       char* lds, int tid) {
  constexpr int ITERS = (128 * 128) / (NTH * 16);
#pragma unroll
  for (int i = 0; i < ITERS; ++i) {
    int slot = i * NTH + tid;
    int off = slot << 4;
    int row = off >> 7;
    int k8 = ((off >> 4) & 7) ^ (row & 7);
    gload_lds16(g + (size_t)row * gstride + (k8 << 4), lds + off);
  }
}

// read 8 contiguous bf16 (16B chunk), undoing swizzle
__device__ __forceinline__ bf16x8 frag_ld(const u16* lds, int row, int q) {
  int off = (row << 7) + ((q ^ (row & 7)) << 4);
  return *(const bf16x8*)((const char*)lds + off);
}

// read 32 contiguous fp8 (two 16B chunks) for f8f6f4 A/B fragment
__device__ __forceinline__ i32x8 frag_ld8(const char* lds, int row, int tq) {
  const char* base = lds + (row << 7);
  uint4 lo = *(const uint4*)(base + (((2 * tq) ^ (row & 7)) << 4));
  uint4 hi = *(const uint4*)(base + (((2 * tq + 1) ^ (row & 7)) << 4));
  i32x8 r;
  r[0] = lo.x; r[1] = lo.y; r[2] = lo.z; r[3] = lo.w;
  r[4] = hi.x; r[5] = hi.y; r[6] = hi.z; r[7] = hi.w;
  return r;
}

__device__ __forceinline__ f32x4 mfma16(bf16x8 a, bf16x8 b, f32x4 c) {
  return __builtin_amdgcn_mfma_f32_16x16x32_bf16(a, b, c, 0, 0, 0);
}

// MX fp8 K=128. A carries 2^11 (A' = A*2048), compensated by A-scale byte
// 116 = 127-11 (E8M0 2^-11). B-scale byte 127 = 1.0.
__device__ __forceinline__ f32x4 mfmaq(i32x8 a, i32x8 b, f32x4 c) {
  return __builtin_amdgcn_mfma_scale_f32_16x16x128_f8f6f4(
      a, b, c, 0, 0, 0, (int)0x74747474, 0, (int)0x7F7F7F7F);
}

// accumulate 8 bf16 (packed in uint4) into f[8] as f32
__device__ __forceinline__ void acc8(uint4 v, float* f) {
  f[0] += __builtin_bit_cast(float, v.x << 16);
  f[1] += __builtin_bit_cast(float, v.x & 0xffff0000u);
  f[2] += __builtin_bit_cast(float, v.y << 16);
  f[3] += __builtin_bit_cast(float, v.y & 0xffff0000u);
  f[4] += __builtin_bit_cast(float, v.z << 16);
  f[5] += __builtin_bit_cast(float, v.z & 0xffff0000u);
  f[6] += __builtin_bit_cast(float, v.w << 16);
  f[7] += __builtin_bit_cast(float, v.w & 0xffff0000u);
}

// ---------------- init kernels ----------------

// A fp32 -> fp8 e4m3 of A*2048 (row-normalized entries ~2.4e-4 are below the
// e4m3 subnormal floor; 2^11 scaling centers them, folded back via MFMA scale)
__global__ void k_convA8(const float* __restrict__ A, unsigned char* __restrict__ Aq) {
  size_t i = ((size_t)blockIdx.x * 256 + threadIdx.x) * 8;
  float4 v0 = *(const float4*)(A + i);
  float4 v1 = *(const float4*)(A + i + 4);
  uint2 o;
  o.x = pk4_fp8(v0.x * 2048.f, v0.y * 2048.f, v0.z * 2048.f, v0.w * 2048.f);
  o.y = pk4_fp8(v1.x * 2048.f, v1.y * 2048.f, v1.z * 2048.f, v1.w * 2048.f);
  *(uint2*)(Aq + i) = o;
}

__global__ void k_zero(float4* __restrict__ p) {
  p[(size_t)blockIdx.x * 256 + threadIdx.x] = make_float4(0.f, 0.f, 0.f, 0.f);
}

// x_0 into HX augmented cols [256,272)
__global__ void k_x0(const float* __restrict__ x, u16* __restrict__ HX) {
  int i = blockIdx.x * 256 + threadIdx.x;  // 65536
  int node = i >> 4, d = i & 15;
  HX[(size_t)node * 320 + 256 + d] = f2b(x[(size_t)node * (NT * 16) + d]);
}

// transpose+convert weights to bf16 B^T layouts. rkTa [1024][320] augmented:
// cols 0..255 = rkernel^T, 256..271 = kernel^T, 272..319 = 0.
__global__ void k_prep(const float* __restrict__ rk, const float* __restrict__ kern,
                       const float* __restrict__ wgh, const float* __restrict__ wgc,
                       const float* __restrict__ whc, const float* __restrict__ whp,
                       const float* __restrict__ wcc, const float* __restrict__ wcp,
                       u16* __restrict__ rkTa, u16* __restrict__ WgTh,
                       u16* __restrict__ WgTc, u16* __restrict__ WhT,
                       u16* __restrict__ WcT) {
  int i = blockIdx.x * 256 + threadIdx.x;
  if (i < 327680) {
    int j = i / 320, k = i % 320;
    float v = k < 256 ? rk[(size_t)k * 1024 + j]
                      : (k < 272 ? kern[(size_t)(k - 256) * 1024 + j] : 0.f);
    rkTa[i] = f2b(v);
    return;
  }
  i -= 327680;
  if (i < 65536) { int j = i >> 8, k = i & 255; WgTh[i] = f2b(wgh[k * 256 + j]); return; }
  i -= 65536;
  if (i < 65536) { int j = i >> 8, k = i & 255; WgTc[i] = f2b(wgc[k * 256 + j]); return; }
  i -= 65536;
  if (i < 131072) {
    int j = i >> 9, k = i & 511;
    WhT[i] = f2b(k < 256 ? whc[k * 256 + j] : whp[(k - 256) * 256 + j]);
    return;
  }
  i -= 131072;
  if (i < 131072) {
    int j = i >> 9, k = i & 511;
    WcT[i] = f2b(k < 256 ? wcc[k * 256 + j] : wcp[(k - 256) * 256 + j]);
  }
}

// ---------------- per-step kernels ----------------

// L1 hetero: bid < 512 -> big GEMM Spb[s] = A @ HC, MX-fp8 K=128, nsplit=4
// (K=1024/block, 8 K-steps), 128x128 tile, 4 waves of 64x64, LDS dbuf.
// bid >= 512 -> LSTM gates (bf16, augmented K=320), independent of big.
__global__ __launch_bounds__(256) void k_l1(
    const unsigned char* __restrict__ AbfQ, const unsigned char* __restrict__ HCTQ,
    u16* __restrict__ Spb, const u16* __restrict__ HX,
    const u16* __restrict__ rkTa, const float* __restrict__ cf32,
    const float* __restrict__ lbias, u16* __restrict__ HG, u16* __restrict__ CG) {
  __shared__ __align__(16) char smem[65536];
  int bid = blockIdx.x;
  int tid = threadIdx.x, lane = tid & 63, w = tid >> 6;
  if (bid < 512) {
    // XCD decode: xcd owns 4 m-slices x all nb x all sb -> 2MB A + 2MB B in L2
    int xcd = bid & 7, j = bid >> 3;
    int mb = xcd * 4 + (j & 3), nb = (j >> 2) & 3, sb = j >> 4;
    int wr = w >> 1, wc = w & 1;
    int m0 = mb * 128, n0 = nb * 128, k0 = sb * 1024;
    char* A0 = smem;            char* A1 = smem + 16384;
    char* B0 = smem + 32768;    char* B1 = smem + 49152;
    const char* Aq = (const char*)AbfQ + (size_t)m0 * 4096 + k0;
    const char* Bq = (const char*)HCTQ + (size_t)n0 * 4096 + k0;
    f32x4 acc[4][4] = {};
    int ar = wr * 64 + (lane & 15);
    int bc = wc * 64 + (lane & 15);
    int tq = lane >> 4;
    stage8<256>(Aq, 4096, A0, tid);
    stage8<256>(Bq, 4096, B0, tid);
    __syncthreads();
    for (int kt = 0; kt < 8; ++kt) {
      char* Ac = (kt & 1) ? A1 : A0;
      char* Bc = (kt & 1) ? B1 : B0;
      if (kt < 7) {
        char* An = (kt & 1) ? A0 : A1;
        char* Bn = (kt & 1) ? B0 : B1;
        stage8<256>(Aq + (kt + 1) * 128, 4096, An, tid);
        stage8<256>(Bq + (kt + 1) * 128, 4096, Bn, tid);
      }
      i32x8 a[4], b[4];
#pragma unroll
      for (int m = 0; m < 4; ++m) a[m] = frag_ld8(Ac, ar + m * 16, tq);
#pragma unroll
      for (int n = 0; n < 4; ++n) b[n] = frag_ld8(Bc, bc + n * 16, tq);
#pragma unroll
      for (int m = 0; m < 4; ++m)
#pragma unroll
        for (int n = 0; n < 4; ++n) acc[m][n] = mfmaq(a[m], b[n], acc[m][n]);
      __syncthreads();
    }
    u16* out = Spb + (size_t)sb * (4096 * 512);
#pragma unroll
    for (int m = 0; m < 4; ++m)
#pragma unroll
      for (int n = 0; n < 4; ++n)
#pragma unroll
        for (int r = 0; r < 4; ++r) {
          int row = m0 + wr * 64 + m * 16 + ((lane >> 4) << 2) + r;
          int col = n0 + wc * 64 + n * 16 + (lane & 15);
          out[(size_t)row * 512 + col] = f2b(acc[m][n][r]);
        }
  } else {
    // ---- gates: z = [h|x|0] @ rkTa + b ; h_cur,c_cur -> HG/CG cols 0..255 ----
    int gb = bid - 512;
    int m0 = (gb & 63) * 64, c0 = (gb >> 6) * 64;
    u16* As = (u16*)smem;             // 8 KB
    u16* Bs = (u16*)(smem + 8192);    // 32 KB
    int wr = w >> 1, wc = w & 1;
    int ar = wr * 32 + (lane & 15);
    int bc = wc * 32 + (lane & 15);
    f32x4 acc[4][2][2] = {};
    for (int kt = 0; kt < 320; kt += 64) {
      stage_tile<64, 256>(HX + (size_t)m0 * 320 + kt, 320, As, tid);
#pragma unroll
      for (int i = 0; i < 8; ++i) {  // 4 gate segments x 64 rows of rkTa
        int slot = i * 256 + tid;
        int off = slot << 4;
        int row = off >> 7;
        int k8 = ((off >> 4) & 7) ^ (row & 7);
        int grow = ((row >> 6) << 8) + c0 + (row & 63);
        gload_lds16((const char*)(rkTa + (size_t)grow * 320 + kt) + (k8 << 4),
                    (char*)Bs + off);
      }
      __syncthreads();
#pragma unroll
      for (int kk = 0; kk < 2; ++kk) {
        int q = kk * 4 + (lane >> 4);
        bf16x8 a0 = frag_ld(As, ar, q);
        bf16x8 a1 = frag_ld(As, ar + 16, q);
#pragma unroll
        for (int s = 0; s < 4; ++s) {
          const u16* B = Bs + s * 4096;
          bf16x8 b0 = frag_ld(B, bc, q);
          bf16x8 b1 = frag_ld(B, bc + 16, q);
          acc[s][0][0] = mfma16(a0, b0, acc[s][0][0]);
          acc[s][0][1] = mfma16(a0, b1, acc[s][0][1]);
          acc[s][1][0] = mfma16(a1, b0, acc[s][1][0]);
          acc[s][1][1] = mfma16(a1, b1, acc[s][1][1]);
        }
      }
      __syncthreads();
    }
#pragma unroll
    for (int m = 0; m < 2; ++m)
#pragma unroll
      for (int r = 0; r < 4; ++r) {
        int node = m0 + wr * 32 + m * 16 + ((lane >> 4) << 2) + r;
#pragma unroll
        for (int n = 0; n < 2; ++n) {
          int hcol = c0 + wc * 32 + n * 16 + (lane & 15);
          float z0 = acc[0][m][n][r] + lbias[hcol];
          float z1 = acc[1][m][n][r] + lbias[256 + hcol];
          float z2 = acc[2][m][n][r] + lbias[512 + hcol];
          float z3 = acc[3][m][n][r] + lbias[768 + hcol];
          float i_ = sigmoid_(z0), f_ = sigmoid_(z1);
          float g_ = tanh_(z2), o_ = sigmoid_(z3);
          float cp = cf32[(size_t)node * 256 + hcol];
          float cc = f_ * cp + i_ * g_;
          float hc = o_ * tanh_(cc);
          HG[(size_t)node * 512 + hcol] = f2b(hc);
          CG[(size_t)node * 512 + hcol] = f2b(cc);
        }
      }
  }
}

// L2: graph GEMM out = tanh(S_half @ Wg + bg), 4-way split-K reduce fused into
// A-staging. m-tile 32: grid 1024 x 256thr.
__global__ __launch_bounds__(256) void k_graph(
    const u16* __restrict__ Spb, const u16* __restrict__ WgTh,
    const u16* __restrict__ WgTc, const float* __restrict__ bgh,
    const float* __restrict__ bgc, u16* __restrict__ HG, u16* __restrict__ CG) {
  __shared__ __align__(16) u16 As[32 * 64];   // 4 KB
  __shared__ __align__(16) u16 Bs[64 * 64];   // 8 KB
  int bid = blockIdx.x, tid = threadIdx.x, lane = tid & 63, w = tid >> 6;
  int zz = bid >> 9;
  int rest = bid & 511;
  int c0 = (rest >> 7) * 64, m0 = (rest & 127) * 32;
  const u16* WT = zz ? WgTc : WgTh;
  const float* bg = zz ? bgc : bgh;
  u16* outp = zz ? CG : HG;
  f32x4 acc[2] = {};
  for (int kt = 0; kt < 256; kt += 64) {
    {
      int srow = tid >> 3, sq = tid & 7;
      const u16* g = Spb + (size_t)(m0 + srow) * 512 + zz * 256 + kt + sq * 8;
      float f[8] = {};
#pragma unroll
      for (int s = 0; s < 4; ++s)
        acc8(*(const uint4*)(g + (size_t)s * (4096 * 512)), f);
      union { u16 u[8]; uint4 v; } o;
#pragma unroll
      for (int e = 0; e < 8; ++e) o.u[e] = f2b(f[e]);
      *(uint4*)((char*)As + (srow << 7) + ((sq ^ (srow & 7)) << 4)) = o.v;
    }
    stage_tile<64, 256>(WT + (size_t)c0 * 256 + kt, 256, Bs, tid);
    __syncthreads();
#pragma unroll
    for (int kk = 0; kk < 2; ++kk) {
      int q = kk * 4 + (lane >> 4);
      bf16x8 b = frag_ld(Bs, w * 16 + (lane & 15), q);
      bf16x8 a0 = frag_ld(As, lane & 15, q);
      bf16x8 a1 = frag_ld(As, 16 + (lane & 15), q);
      acc[0] = mfma16(a0, b, acc[0]);
      acc[1] = mfma16(a1, b, acc[1]);
    }
    __syncthreads();
  }
#pragma unroll
  for (int m = 0; m < 2; ++m)
#pragma unroll
    for (int r = 0; r < 4; ++r) {
      int row = m0 + m * 16 + ((lane >> 4) << 2) + r;
      int col = c0 + w * 16 + (lane & 15);
      outp[(size_t)row * 512 + 256 + col] = f2b(tanh_(acc[m][r] + bg[col]));
    }
}

// L3: h_upd/c_upd = sigmoid([cur|graph] @ [Wcur;Wprev] + b). m-tile 16:
// grid(256,2) x 256thr. z=0 emits out_pred + HX h-cols + x_{t+1}; fp8 HCTQ.
__global__ __launch_bounds__(256) void k_merge(
    const u16* __restrict__ HG, const u16* __restrict__ CG,
    const u16* __restrict__ WhT, const u16* __restrict__ WcT,
    const float* __restrict__ bh, const float* __restrict__ bcv,
    const float* __restrict__ Wout, const float* __restrict__ bout,
    u16* __restrict__ HX, unsigned char* __restrict__ HCTQ,
    float* __restrict__ cf32, float* __restrict__ dout,
    const float* __restrict__ xin, int t) {
  __shared__ __align__(16) u16 As[16 * 64];    // 2 KB
  __shared__ __align__(16) u16 Bs[256 * 64];   // 32 KB
  __shared__ float outac[32];
  int z = blockIdx.y;
  const u16* Ain = z ? CG : HG;
  const u16* WT = z ? WcT : WhT;
  const float* bb = z ? bcv : bh;
  int tid = threadIdx.x, lane = tid & 63, w = tid >> 6;
  int m0 = blockIdx.x * 16;
  if (tid < 32) outac[tid] = 0.f;
  f32x4 acc[4] = {};
  int bcol = w * 64 + (lane & 15);
  for (int kt = 0; kt < 512; kt += 64) {
    if (tid < 128) {
      int row = tid >> 3, q = tid & 7;
      int k8 = q ^ (row & 7);
      gload_lds16(Ain + (size_t)(m0 + row) * 512 + kt + k8 * 8,
                  (char*)As + (tid << 4));
    }
    stage_tile<256, 256>(WT + kt, 512, Bs, tid);
    __syncthreads();
#pragma unroll
    for (int kk = 0; kk < 2; ++kk) {
      int q = kk * 4 + (lane >> 4);
      bf16x8 a0 = frag_ld(As, lane & 15, q);
      bf16x8 b0 = frag_ld(Bs, bcol, q);
      bf16x8 b1 = frag_ld(Bs, bcol + 16, q);
      bf16x8 b2 = frag_ld(Bs, bcol + 32, q);
      bf16x8 b3 = frag_ld(Bs, bcol + 48, q);
      acc[0] = mfma16(a0, b0, acc[0]);
      acc[1] = mfma16(a0, b1, acc[1]);
      acc[2] = mfma16(a0, b2, acc[2]);
      acc[3] = mfma16(a0, b3, acc[3]);
    }
    __syncthreads();
  }
  int g = lane >> 4;
  float hv[4][4];
#pragma unroll
  for (int n = 0; n < 4; ++n) {
    int col = w * 64 + n * 16 + (lane & 15);
#pragma unroll
    for (int r = 0; r < 4; ++r) hv[n][r] = sigmoid_(acc[n][r] + bb[col]);
  }
  if (z == 0) {
#pragma unroll
    for (int r = 0; r < 4; ++r) {
      int row_local = (g << 2) + r;
      int node = m0 + row_local;
      float p0 = 0.f, p1 = 0.f;
#pragma unroll
      for (int n = 0; n < 4; ++n) {
        int col = w * 64 + n * 16 + (lane & 15);
        p0 += hv[n][r] * Wout[col * 2];
        p1 += hv[n][r] * Wout[col * 2 + 1];
        HX[(size_t)node * 320 + col] = f2b(hv[n][r]);
      }
#pragma unroll
      for (int off2 = 1; off2 < 16; off2 <<= 1) {
        p0 += __shfl_xor(p0, off2);
        p1 += __shfl_xor(p1, off2);
      }
      if ((lane & 15) == 0) {
        atomicAdd(&outac[row_local * 2], p0);
        atomicAdd(&outac[row_local * 2 + 1], p1);
      }
    }
#pragma unroll
    for (int n = 0; n < 4; ++n) {
      int col = w * 64 + n * 16 + (lane & 15);
      unsigned int pk = pk4_fp8(hv[n][0], hv[n][1], hv[n][2], hv[n][3]);
      *(unsigned int*)(HCTQ + (size_t)col * 4096 + m0 + (g << 2)) = pk;
    }
  } else {
#pragma unroll
    for (int n = 0; n < 4; ++n) {
      int col = w * 64 + n * 16 + (lane & 15);
#pragma unroll
      for (int r = 0; r < 4; ++r)
        cf32[(size_t)(m0 + (g << 2) + r) * 256 + col] = hv[n][r];
      unsigned int pk = pk4_fp8(hv[n][0], hv[n][1], hv[n][2], hv[n][3]);
      *(unsigned int*)(HCTQ + (size_t)(256 + col) * 4096 + m0 + (g << 2)) = pk;
    }
  }
  if (z == 0 && t + 1 < NT && tid < 256) {
    int row = tid >> 4, d = tid & 15;
    HX[(size_t)(m0 + row) * 320 + 256 + d] =
        f2b(xin[(size_t)(m0 + row) * (NT * 16) + (t + 1) * 16 + d]);
  }
  __syncthreads();
  if (z == 0 && tid < 32) {
    int row = tid >> 1, pp = tid & 1;
    dout[(size_t)(m0 + row) * (NT * 2) + t * 2 + pp] = outac[tid] + bout[pp];
  }
}

extern "C" void kernel_launch(void* const* d_in, const int* in_sizes, int n_in,
                              void* d_out, int out_size, void* d_ws, size_t ws_size,
                              hipStream_t stream) {
  (void)in_sizes; (void)n_in; (void)out_size; (void)ws_size;
  const float* inputs = (const float*)d_in[0];
  const float* A      = (const float*)d_in[1];
  const float* kern   = (const float*)d_in[2];
  const float* rk     = (const float*)d_in[3];
  const float* lbias  = (const float*)d_in[4];
  const float* wgh    = (const float*)d_in[5];
  const float* bgh    = (const float*)d_in[6];
  const float* wgc    = (const float*)d_in[7];
  const float* bgc    = (const float*)d_in[8];
  const float* whc    = (const float*)d_in[9];
  const float* whp    = (const float*)d_in[10];
  const float* bh     = (const float*)d_in[11];
  const float* wcc    = (const float*)d_in[12];
  const float* wcp    = (const float*)d_in[13];
  const float* bcv    = (const float*)d_in[14];
  const float* wout   = (const float*)d_in[15];
  const float* bout   = (const float*)d_in[16];
  float* dout = (float*)d_out;

  // Total 52,297,728 B -- guaranteed fit (R4 proved ws >= 54.39 MB). nsplit=4.
  char* p = (char*)d_ws;
  unsigned char* AbfQ = (unsigned char*)p; p += (size_t)4096 * 4096;  // fp8 A*2^11
  u16* HX   = (u16*)p; p += (size_t)4096 * 320 * 2;    // [h(256)|x(16)|0(48)] bf16
  unsigned char* HCTQ = (unsigned char*)p; p += (size_t)512 * 4096;   // fp8 B^T
  float* cf32 = (float*)p; p += (size_t)4096 * 256 * 4;
  u16* Spb  = (u16*)p; p += (size_t)4 * 4096 * 512 * 2;  // bf16 split-K partials
  u16* HG   = (u16*)p; p += (size_t)4096 * 512 * 2;    // [h_cur|h_graph] bf16
  u16* CG   = (u16*)p; p += (size_t)4096 * 512 * 2;    // [c_cur|c_graph] bf16
  u16* rkTa = (u16*)p; p += (size_t)1024 * 320 * 2;    // augmented [rk;kern;0]
  u16* WgThp = (u16*)p; p += (size_t)65536 * 2;
  u16* WgTcp = (u16*)p; p += (size_t)65536 * 2;
  u16* WhTp  = (u16*)p; p += (size_t)131072 * 2;
  u16* WcTp  = (u16*)p; p += (size_t)131072 * 2;

  k_convA8<<<8192, 256, 0, stream>>>(A, AbfQ);
  // zero HX + HCTQ + cf32 (contiguous, 8,912,896 B = 557,056 float4)
  k_zero<<<2176, 256, 0, stream>>>((float4*)HX);
  k_x0<<<256, 256, 0, stream>>>(inputs, HX);
  k_prep<<<2816, 256, 0, stream>>>(rk, kern, wgh, wgc, whc, whp, wcc, wcp,
                                   rkTa, WgThp, WgTcp, WhTp, WcTp);

  for (int t = 0; t < NT; ++t) {
    k_l1<<<768, 256, 0, stream>>>(AbfQ, HCTQ, Spb, HX, rkTa, cf32, lbias, HG, CG);
    k_graph<<<1024, 256, 0, stream>>>(Spb, WgThp, WgTcp, bgh, bgc, HG, CG);
    k_merge<<<dim3(256, 2), 256, 0, stream>>>(HG, CG, WhTp, WcTp, bh, bcv, wout,
                                              bout, HX, HCTQ, cf32, dout, inputs, t);
  }
}